// Round 13
// baseline (49503.180 us; speedup 1.0000x reference)
//
#include <hip/hip_runtime.h>
#include <stdint.h>

#define H4T 2048
#define BATCHN 32
#define TSTEPS 1000
#define NBLK 256
#define NTHR 512

typedef float f2 __attribute__((ext_vector_type(2)));
typedef unsigned long long u64;

// ws layout:
//   [0, 256K)            : h buffer 0  ([i][b] floats)
//   [256K, 512K)         : h buffer 1
//   [512K, 512K+1M)      : arrival flags, 1000 steps x 256 blocks x u32

__device__ __forceinline__ float ht_clip(float w) {
  return fminf(fmaxf(w, 1e-15f), 1.0f);
}

// W_rec[j, i] for j = g*512 + jj. Block-sparse per reference.
__device__ float wval(int g, int jj, int i,
                      const float* s2s_f, const float* t2s, const float* a2s,
                      const float* s2n, const float* n2t,
                      const float* t2a, const float* a2a) {
  int ig = i >> 9;
  int ii = i & 511;
  float v = 0.0f;
  if (g == 0) {
    if (ig == 0)      v = -s2s_f[jj * 512 + ii];
    else if (ig == 2) v = (jj >= 256) ? ht_clip(t2s[jj * 512 + ii]) : 0.0f;
    else if (ig == 3) v = (ii < 359) ? ht_clip(a2s[jj * 512 + ii]) : 0.0f;
  } else if (g == 1) {
    if (ig == 0)      v = -ht_clip(s2n[jj * 512 + ii]);
  } else if (g == 2) {
    if (ig == 1)      v = -ht_clip(n2t[jj * 512 + ii]);
  } else {
    if (ig == 2)      v = ht_clip(t2a[jj * 512 + ii]);
    else if (ig == 3) v = ht_clip(a2a[jj * 512 + ii]) * ((ii < 359) ? 1.0f : -1.0f);
  }
  return v;
}

__global__ void prep_h0(const float* __restrict__ hn, float* __restrict__ hbuf0) {
  int e = blockIdx.x * blockDim.x + threadIdx.x;
  if (e < BATCHN * H4T) {
    int b = e >> 11;
    int j = e & 2047;
    hbuf0[j * 32 + b] = hn[e];   // [i][b] layout
  }
}

// two DPP quad_perm rounds: every lane ends with the sum over its 4-lane quad
__device__ __forceinline__ float quad_sum(float x) {
  int t = __builtin_amdgcn_mov_dpp(__builtin_bit_cast(int, x), 0xB1, 0xF, 0xF, false); // [1,0,3,2]
  x += __builtin_bit_cast(float, t);
  t = __builtin_amdgcn_mov_dpp(__builtin_bit_cast(int, x), 0x4E, 0xF, 0xF, false);     // [2,3,0,1]
  x += __builtin_bit_cast(float, t);
  return x;
}

// MAP: 0 -> i4 = ibase4 + fi4; 1 -> fi4<128 ? fi4 : fi4+128 (E1536);
//      2 -> fi4<128 ? fi4 : fi4+256 (E1024 skip-middle)
template<int NCOLS, int NC, int IEXT, int MAP, int LOG2NCOLS>
__device__ __forceinline__ void run_group(
    int g, int j0, int ibase4, float tonicv,
    const float* __restrict__ inp, const float* __restrict__ inhib,
    const float* s2s_f, const float* t2s, const float* a2s,
    const float* s2n, const float* n2t, const float* t2a, const float* a2a,
    const float* __restrict__ inpw,
    float* __restrict__ out_hn, float* __restrict__ out_rnn,
    float* hbuf0, float* hbuf1, unsigned int* __restrict__ arr,
    u64* red, float* iwl)
{
  constexpr int SLICE4 = IEXT / 128;   // i4-chunks per thread (chunks of 4 i)
  constexpr int PAIRS  = NC * 4;       // batch-pairs per (wave,cg,bg) class
  constexpr int LGN    = (NC == 4) ? 2 : (NC == 2) ? 1 : 0;

  const int tid  = threadIdx.x;
  const int bid  = blockIdx.x;
  const int w    = tid >> 6;
  const int lane = tid & 63;
  const int cg   = lane >> 4;         // col-group 0..3
  const int bg   = (lane >> 2) & 3;   // batch-group 0..3 (8 batches each)
  const int jw   = lane & 3;          // jl within wave (quad dim)
  const int jl   = w * 4 + jw;        // 0..31 i-slice
  const int classIdx = (w * 4 + cg) * 4 + bg;

  auto mapi4 = [&](int fi4) {
    return (MAP == 1) ? ((fi4 < 128) ? fi4 : fi4 + 128)
         : (MAP == 2) ? ((fi4 < 128) ? fi4 : fi4 + 256)
                      : ibase4 + fi4;
  };

  // ---- one-time: this thread's constant W fragment into REGISTERS ----
  float Wr[NC][SLICE4 * 4];
#pragma unroll
  for (int ci = 0; ci < NC; ++ci) {
    int c = j0 + cg * NC + ci;
#pragma unroll
    for (int s = 0; s < SLICE4; ++s) {
      int i4 = mapi4(s * 32 + jl);
#pragma unroll
      for (int q = 0; q < 4; ++q)
        Wr[ci][s * 4 + q] = wval(g, c & 511, i4 * 4 + q, s2s_f, t2s, a2s, s2n, n2t, t2a, a2a);
    }
  }
  if (tid < NCOLS) {
    int j = j0 + tid;
    iwl[tid] = (j >= 256 && j < 512) ? ht_clip(inpw[j]) : 0.0f;
  }

  // ---- per-thread update state (threads tid < NCOLS*32) ----
  const int uc  = tid & (NCOLS - 1);
  const int upb = tid >> LOG2NCOLS;
  const int rj  = j0 + uc;
  float hold = 0.0f, inh_r = 0.0f, iv_r = 0.0f;
  if (tid < NCOLS * 32) {
    hold  = hbuf0[rj * 32 + upb];
    inh_r = inhib[(size_t)upb * (TSTEPS * H4T) + rj];
    iv_r  = inp[upb * TSTEPS];
  }
  __syncthreads();

  int cur = 0;

  for (int t = 0; t < TSTEPS; ++t) {
    const float* hb  = cur ? hbuf1 : hbuf0;
    float*       hbn = cur ? hbuf0 : hbuf1;
    const u64* __restrict__ hb8 = (const u64*)hb;

    f2 acc2[NC][4];
#pragma unroll
    for (int ci = 0; ci < NC; ++ci)
#pragma unroll
      for (int k = 0; k < 4; ++k) acc2[ci][k] = (f2){0.0f, 0.0f};

    auto loadc = [&](int s, u64* P) {
      int i4 = mapi4(s * 32 + jl);
      const u64* hp = hb8 + (size_t)i4 * 64 + bg * 4;   // u64 idx: (i4*4+q)*16 + bg*4 + k
#pragma unroll
      for (int q = 0; q < 4; ++q)
#pragma unroll
        for (int k = 0; k < 4; ++k)
          P[q * 4 + k] = __hip_atomic_load(hp + q * 16 + k,
                           __ATOMIC_RELAXED, __HIP_MEMORY_SCOPE_AGENT);
    };
    auto fmac = [&](int s, const u64* P) {
#pragma unroll
      for (int q = 0; q < 4; ++q)
#pragma unroll
        for (int k = 0; k < 4; ++k) {
          f2 h2 = __builtin_bit_cast(f2, P[q * 4 + k]);
#pragma unroll
          for (int ci = 0; ci < NC; ++ci) {
            float wv = Wr[ci][s * 4 + q];
            acc2[ci][k] = __builtin_elementwise_fma((f2){wv, wv}, h2, acc2[ci][k]);
          }
        }
    };

    // ---- software-pipelined: sc1 h loads (ping-pong) + packed FMA ----
    u64 pA[16], pB[16];
    loadc(0, pA);
#pragma unroll
    for (int s = 0; s < SLICE4; ++s) {
      if ((s & 1) == 0) {
        if (s + 1 < SLICE4) loadc(s + 1, pB);
        fmac(s, pA);
      } else {
        if (s + 1 < SLICE4) loadc(s + 1, pA);
        fmac(s, pB);
      }
    }

    // ---- in-quad DPP reduce over jw (jl within wave) ----
#pragma unroll
    for (int ci = 0; ci < NC; ++ci)
#pragma unroll
      for (int k = 0; k < 4; ++k) {
        acc2[ci][k].x = quad_sum(acc2[ci][k].x);
        acc2[ci][k].y = quad_sum(acc2[ci][k].y);
      }

    // ---- packed per-class write: lane writes its NC pairs (p = jw*NC + k2) ----
    {
      u64* rp = red + (size_t)classIdx * PAIRS;
#define WRJ(JW)                                                                  \
      if (jw == JW) {                                                            \
        _Pragma("unroll")                                                        \
        for (int k2 = 0; k2 < NC; ++k2)                                          \
          rp[JW * NC + k2] =                                                     \
            __builtin_bit_cast(u64, acc2[(JW * NC + k2) >> 2][(JW * NC + k2) & 3]); \
      }
      WRJ(0) WRJ(1) WRJ(2) WRJ(3)
#undef WRJ
    }
    __syncthreads();

    // ---- final: sum 8 wave-partials, pointwise update, stores ----
    if (tid < NCOLS * 32) {
      const int ciu = uc & (NC - 1);
      const int cgu = uc >> LGN;
      const int p   = ciu * 4 + ((upb & 7) >> 1);
      const int bgu = upb >> 3;
      const int hf  = upb & 1;
      const float* rf = (const float*)red;
      float s = 0.0f;
#pragma unroll
      for (int w8 = 0; w8 < 8; ++w8)
        s += rf[((((size_t)(w8 * 4 + cgu) * 4 + bgu) * PAIRS + p) << 1) + hf];
      float d    = inh_r + tonicv + iv_r * iwl[uc];
      float hnew = fmaxf(0.0f, fmaf(0.01f, s + d - hold, hold));
      hold = hnew;
      __hip_atomic_store(&hbn[rj * 32 + upb], hnew,
                         __ATOMIC_RELAXED, __HIP_MEMORY_SCOPE_AGENT);
      out_rnn[(size_t)upb * (TSTEPS * H4T) + (size_t)t * H4T + rj] = hnew;
      if (t == TSTEPS - 1) out_hn[upb * H4T + rj] = hnew;
    }
    __syncthreads();   // drains vmcnt: h stores MALL-acked; red reads done

    // ---- arrival flag; prefetch t+1 drive under the wait ----
    if (tid == 0)
      __hip_atomic_store(&arr[t * NBLK + bid], 1u,
                         __ATOMIC_RELAXED, __HIP_MEMORY_SCOPE_AGENT);
    if (tid < NCOLS * 32) {
      int tn = (t + 1 < TSTEPS) ? t + 1 : t;
      inh_r = inhib[(size_t)upb * (TSTEPS * H4T) + (size_t)tn * H4T + rj];
      iv_r  = inp[upb * TSTEPS + tn];
    }

    // ---- flat barrier: every wave polls independently (R7-proven) ----
    {
      const u64* fp = (const u64*)(arr + t * NBLK);
      const u64 want = 0x0000000100000001ULL;
      for (;;) {
        u64 a0 = __hip_atomic_load(fp + lane, __ATOMIC_RELAXED, __HIP_MEMORY_SCOPE_AGENT);
        u64 a1 = __hip_atomic_load(fp + 64 + lane, __ATOMIC_RELAXED, __HIP_MEMORY_SCOPE_AGENT);
        if (__all(a0 == want && a1 == want)) break;
        __builtin_amdgcn_s_sleep(1);
      }
    }
    cur ^= 1;
  }
}

__global__ __launch_bounds__(NTHR, 2) void rnn_persistent(
    const float* __restrict__ inp, const float* __restrict__ inhib,
    const float* s2s_f, const float* t2s, const float* a2s,
    const float* s2n, const float* n2t, const float* t2a, const float* a2a,
    const float* __restrict__ inpw,
    float* __restrict__ out_hn, float* __restrict__ out_rnn,
    float* hbuf0, float* hbuf1, unsigned int* arr)
{
  __shared__ u64 red[128 * 16];   // 128 classes x <=16 pairs = 16 KB
  __shared__ float iwl[16];

  int bid = blockIdx.x;
  if (bid < 64) {
    run_group<4, 1, 1024, 2, 2>(0, bid * 4, 0, 0.0f,
        inp, inhib, s2s_f, t2s, a2s, s2n, n2t, t2a, a2a, inpw,
        out_hn, out_rnn, hbuf0, hbuf1, arr, red, iwl);
  } else if (bid < 128) {
    run_group<4, 1, 1536, 1, 2>(0, bid * 4, 0, 0.0f,
        inp, inhib, s2s_f, t2s, a2s, s2n, n2t, t2a, a2a, inpw,
        out_hn, out_rnn, hbuf0, hbuf1, arr, red, iwl);
  } else if (bid < 160) {
    run_group<16, 4, 512, 0, 4>(1, 512 + (bid - 128) * 16, 0, 0.7f,
        inp, inhib, s2s_f, t2s, a2s, s2n, n2t, t2a, a2a, inpw,
        out_hn, out_rnn, hbuf0, hbuf1, arr, red, iwl);
  } else if (bid < 192) {
    run_group<16, 4, 512, 0, 4>(2, 1024 + (bid - 160) * 16, 128, 1.0f,
        inp, inhib, s2s_f, t2s, a2s, s2n, n2t, t2a, a2a, inpw,
        out_hn, out_rnn, hbuf0, hbuf1, arr, red, iwl);
  } else {
    run_group<8, 2, 1024, 0, 3>(3, 1536 + (bid - 192) * 8, 256, 0.0f,
        inp, inhib, s2s_f, t2s, a2s, s2n, n2t, t2a, a2a, inpw,
        out_hn, out_rnn, hbuf0, hbuf1, arr, red, iwl);
  }
}

extern "C" void kernel_launch(void* const* d_in, const int* in_sizes, int n_in,
                              void* d_out, int out_size, void* d_ws, size_t ws_size,
                              hipStream_t stream) {
  const float* inp   = (const float*)d_in[0];   // [32,1000,1]
  const float* hn    = (const float*)d_in[1];   // [1,32,2048]
  const float* inhib = (const float*)d_in[2];   // [32,1000,2048]
  // d_in[3] = str2str_w (x0.0 in reference -> unused)
  const float* t2a   = (const float*)d_in[4];
  const float* t2s   = (const float*)d_in[5];
  const float* a2a   = (const float*)d_in[6];
  const float* a2s   = (const float*)d_in[7];
  const float* s2n   = (const float*)d_in[8];
  const float* n2t   = (const float*)d_in[9];
  const float* inpw  = (const float*)d_in[10];
  const float* s2s_f = (const float*)d_in[11];

  float* out_hn  = (float*)d_out;               // [1,32,2048]
  float* out_rnn = out_hn + BATCHN * H4T;       // [32,1000,2048]

  float* hbuf0 = (float*)d_ws;
  float* hbuf1 = hbuf0 + BATCHN * H4T;
  unsigned int* arr = (unsigned int*)((char*)d_ws + 512 * 1024);

  hipMemsetAsync(arr, 0, TSTEPS * NBLK * sizeof(unsigned int), stream);
  prep_h0<<<256, 256, 0, stream>>>(hn, hbuf0);
  rnn_persistent<<<NBLK, NTHR, 0, stream>>>(
      inp, inhib, s2s_f, t2s, a2s, s2n, n2t, t2a, a2a, inpw,
      out_hn, out_rnn, hbuf0, hbuf1, arr);
}

// Round 14
// 38032.605 us; speedup vs baseline: 1.3016x; 1.3016x over previous
//
#include <hip/hip_runtime.h>
#include <stdint.h>

#define H4T 2048
#define BATCHN 32
#define TSTEPS 1000
#define NBLK 256
#define NTHR 512

typedef float f2 __attribute__((ext_vector_type(2)));
typedef unsigned long long u64;

// ws layout:
//   [0, 256K)            : h buffer 0  ([i][b] floats)
//   [256K, 512K)         : h buffer 1
//   [512K, 512K+1M)      : arrival flags, 1000 steps x 256 blocks x u32

__device__ __forceinline__ float ht_clip(float w) {
  return fminf(fmaxf(w, 1e-15f), 1.0f);
}

// W_rec[j, i] for j = g*512 + jj. Block-sparse per reference.
__device__ float wval(int g, int jj, int i,
                      const float* s2s_f, const float* t2s, const float* a2s,
                      const float* s2n, const float* n2t,
                      const float* t2a, const float* a2a) {
  int ig = i >> 9;
  int ii = i & 511;
  float v = 0.0f;
  if (g == 0) {
    if (ig == 0)      v = -s2s_f[jj * 512 + ii];
    else if (ig == 2) v = (jj >= 256) ? ht_clip(t2s[jj * 512 + ii]) : 0.0f;
    else if (ig == 3) v = (ii < 359) ? ht_clip(a2s[jj * 512 + ii]) : 0.0f;
  } else if (g == 1) {
    if (ig == 0)      v = -ht_clip(s2n[jj * 512 + ii]);
  } else if (g == 2) {
    if (ig == 1)      v = -ht_clip(n2t[jj * 512 + ii]);
  } else {
    if (ig == 2)      v = ht_clip(t2a[jj * 512 + ii]);
    else if (ig == 3) v = ht_clip(a2a[jj * 512 + ii]) * ((ii < 359) ? 1.0f : -1.0f);
  }
  return v;
}

__global__ void prep_h0(const float* __restrict__ hn, float* __restrict__ hbuf0) {
  int e = blockIdx.x * blockDim.x + threadIdx.x;
  if (e < BATCHN * H4T) {
    int b = e >> 11;
    int j = e & 2047;
    hbuf0[j * 32 + b] = hn[e];   // [i][b] layout
  }
}

// butterfly over lane bits {0,1,3}: xor1,xor2 via quad_perm, xor8 via row_ror:8
__device__ __forceinline__ float red3(float v) {
  int t;
  t = __builtin_amdgcn_mov_dpp(__builtin_bit_cast(int, v), 0xB1, 0xF, 0xF, false);  // quad [1,0,3,2]
  v += __builtin_bit_cast(float, t);
  t = __builtin_amdgcn_mov_dpp(__builtin_bit_cast(int, v), 0x4E, 0xF, 0xF, false);  // quad [2,3,0,1]
  v += __builtin_bit_cast(float, t);
  t = __builtin_amdgcn_mov_dpp(__builtin_bit_cast(int, v), 0x128, 0xF, 0xF, false); // row_ror:8 == l^8 in row16
  v += __builtin_bit_cast(float, t);
  return v;
}

// MAP: 0 -> i = ibase + fi; 1 -> fi<512?fi:fi+512 (E1536); 2 -> fi<512?fi:fi+1024 (E1024)
template<int NCOLS, int NS, int MAP, int LOG2NC>
__device__ __forceinline__ void run_group(
    int g, int j0, int ibase, float tonicv,
    const float* __restrict__ inp, const float* __restrict__ inhib,
    const float* s2s_f, const float* t2s, const float* a2s,
    const float* s2n, const float* n2t, const float* t2a, const float* a2a,
    const float* __restrict__ inpw,
    float* __restrict__ out_hn, float* __restrict__ out_rnn,
    float* hbuf0, float* hbuf1, unsigned int* __restrict__ arr,
    float* red)
{
  constexpr int NCH = NS / 4;                 // chunks of 4 slots (one float4 each)
  const int tid  = threadIdx.x;
  const int bid  = blockIdx.x;
  const int w    = tid >> 6;
  const int lane = tid & 63;
  const int i8c  = (lane & 3) | ((lane >> 1) & 4);        // lane bits 0,1,3
  const int b4g  = ((lane >> 2) & 1) | ((lane >> 3) & 6); // lane bits 2,4,5
  const int wbase = w * (NS * 8);

  auto mapfi = [&](int fi) {
    return (MAP == 1) ? ((fi < 512) ? fi : fi + 512)
         : (MAP == 2) ? ((fi < 512) ? fi : fi + 1024)
                      : ibase + fi;
  };

  // ---- one-time: this thread's W fragment into REGISTERS (no duplication) ----
  float Wr[NCOLS][NS];
#pragma unroll
  for (int ci = 0; ci < NCOLS; ++ci) {
    int c = (j0 + ci) & 511;
#pragma unroll
    for (int s = 0; s < NS; ++s)
      Wr[ci][s] = wval(g, c, mapfi(wbase + s * 8 + i8c),
                       s2s_f, t2s, a2s, s2n, n2t, t2a, a2a);
  }

  // ---- update-thread state in registers ----
  const int uc  = tid & (NCOLS - 1);
  const int upb = tid >> LOG2NC;
  const int rj  = j0 + uc;
  float hold = 0.0f, inh_r = 0.0f, iv_r = 0.0f, iw_r = 0.0f;
  if (tid < NCOLS * 32) {
    hold  = hbuf0[rj * 32 + upb];
    inh_r = inhib[(size_t)upb * (TSTEPS * H4T) + rj];
    iv_r  = inp[upb * TSTEPS];
    iw_r  = (rj >= 256 && rj < 512) ? ht_clip(inpw[rj]) : 0.0f;
  }
  __syncthreads();

  int cur = 0;
  for (int t = 0; t < TSTEPS; ++t) {
    const float* hb  = cur ? hbuf1 : hbuf0;
    float*       hbn = cur ? hbuf0 : hbuf1;
    const u64* __restrict__ hb8 = (const u64*)hb;

    f2 acc2[NCOLS][2];
#pragma unroll
    for (int ci = 0; ci < NCOLS; ++ci) {
      acc2[ci][0] = (f2){0.0f, 0.0f};
      acc2[ci][1] = (f2){0.0f, 0.0f};
    }

    u64 pA[8], pB[8];
    auto loadc = [&](int ch, u64* P) {
#pragma unroll
      for (int q = 0; q < 4; ++q) {
        int ri = mapfi(wbase + (ch * 4 + q) * 8 + i8c);
        const u64* hp = hb8 + (size_t)ri * 16 + b4g * 2;
        P[2 * q]     = __hip_atomic_load(hp,     __ATOMIC_RELAXED, __HIP_MEMORY_SCOPE_AGENT);
        P[2 * q + 1] = __hip_atomic_load(hp + 1, __ATOMIC_RELAXED, __HIP_MEMORY_SCOPE_AGENT);
      }
    };
    auto fmac = [&](int ch, const u64* P) {
#pragma unroll
      for (int q = 0; q < 4; ++q) {
        f2 lo = __builtin_bit_cast(f2, P[2 * q]);
        f2 hi = __builtin_bit_cast(f2, P[2 * q + 1]);
#pragma unroll
        for (int ci = 0; ci < NCOLS; ++ci) {
          float wv = Wr[ci][ch * 4 + q];
          acc2[ci][0] = __builtin_elementwise_fma((f2){wv, wv}, lo, acc2[ci][0]);
          acc2[ci][1] = __builtin_elementwise_fma((f2){wv, wv}, hi, acc2[ci][1]);
        }
      }
    };

    // software-pipelined: load chunk k+1 while FMA on chunk k (static ping-pong)
    loadc(0, pA);
#pragma unroll
    for (int ch = 0; ch < NCH; ++ch) {
      if ((ch & 1) == 0) {
        if (ch + 1 < NCH) loadc(ch + 1, pB);
        fmac(ch, pA);
      } else {
        if (ch + 1 < NCH) loadc(ch + 1, pA);
        fmac(ch, pB);
      }
    }

    // ---- all-VALU butterfly over i8; 1/8 lanes write one float4 per col ----
#pragma unroll
    for (int ci = 0; ci < NCOLS; ++ci) {
      float4 v;
      v.x = red3(acc2[ci][0][0]);
      v.y = red3(acc2[ci][0][1]);
      v.z = red3(acc2[ci][1][0]);
      v.w = red3(acc2[ci][1][1]);
      if (i8c == 0)
        *(float4*)&red[(w * NCOLS + ci) * 36 + b4g * 4] = v;
    }
    __syncthreads();

    // ---- final: sum 8 wave-partials, pointwise update, stores ----
    if (tid < NCOLS * 32) {
      float s = 0.0f;
#pragma unroll
      for (int w8 = 0; w8 < 8; ++w8)
        s += red[(w8 * NCOLS + uc) * 36 + upb];
      float d    = inh_r + tonicv + iv_r * iw_r;
      float hnew = fmaxf(0.0f, fmaf(0.01f, s + d - hold, hold));
      hold = hnew;
      __hip_atomic_store(&hbn[rj * 32 + upb], hnew,
                         __ATOMIC_RELAXED, __HIP_MEMORY_SCOPE_AGENT);
      out_rnn[(size_t)upb * (TSTEPS * H4T) + (size_t)t * H4T + rj] = hnew;
      if (t == TSTEPS - 1) out_hn[upb * H4T + rj] = hnew;
    }
    __syncthreads();   // drains vmcnt: all waves' h stores MALL-acked

    // ---- arrival flag; prefetch t+1 drive under the wait ----
    if (tid == 0)
      __hip_atomic_store(&arr[t * NBLK + bid], 1u,
                         __ATOMIC_RELAXED, __HIP_MEMORY_SCOPE_AGENT);
    if (tid < NCOLS * 32) {
      int tn = (t + 1 < TSTEPS) ? t + 1 : t;
      inh_r = inhib[(size_t)upb * (TSTEPS * H4T) + (size_t)tn * H4T + rj];
      iv_r  = inp[upb * TSTEPS + tn];
    }

    // ---- flat barrier: every wave polls independently (R7-proven) ----
    {
      const u64* fp = (const u64*)(arr + t * NBLK);
      const u64 want = 0x0000000100000001ULL;
      for (;;) {
        u64 a0 = __hip_atomic_load(fp + lane,      __ATOMIC_RELAXED, __HIP_MEMORY_SCOPE_AGENT);
        u64 a1 = __hip_atomic_load(fp + 64 + lane, __ATOMIC_RELAXED, __HIP_MEMORY_SCOPE_AGENT);
        if (__all(a0 == want && a1 == want)) break;
        __builtin_amdgcn_s_sleep(1);
      }
    }
    cur ^= 1;
  }
}

__global__ __launch_bounds__(NTHR, 2) void rnn_persistent(
    const float* __restrict__ inp, const float* __restrict__ inhib,
    const float* s2s_f, const float* t2s, const float* a2s,
    const float* s2n, const float* n2t, const float* t2a, const float* a2a,
    const float* __restrict__ inpw,
    float* __restrict__ out_hn, float* __restrict__ out_rnn,
    float* hbuf0, float* hbuf1, unsigned int* arr)
{
  __shared__ __align__(16) float red[8 * 16 * 36];   // 18.4 KB worst case
  int bid = blockIdx.x;
  if (bid < 64) {
    run_group<4, 16, 2, 2>(0, bid * 4, 0, 0.0f,
        inp, inhib, s2s_f, t2s, a2s, s2n, n2t, t2a, a2a, inpw,
        out_hn, out_rnn, hbuf0, hbuf1, arr, red);
  } else if (bid < 128) {
    run_group<4, 24, 1, 2>(0, bid * 4, 0, 0.0f,
        inp, inhib, s2s_f, t2s, a2s, s2n, n2t, t2a, a2a, inpw,
        out_hn, out_rnn, hbuf0, hbuf1, arr, red);
  } else if (bid < 160) {
    run_group<16, 8, 0, 4>(1, 512 + (bid - 128) * 16, 0, 0.7f,
        inp, inhib, s2s_f, t2s, a2s, s2n, n2t, t2a, a2a, inpw,
        out_hn, out_rnn, hbuf0, hbuf1, arr, red);
  } else if (bid < 192) {
    run_group<16, 8, 0, 4>(2, 1024 + (bid - 160) * 16, 512, 1.0f,
        inp, inhib, s2s_f, t2s, a2s, s2n, n2t, t2a, a2a, inpw,
        out_hn, out_rnn, hbuf0, hbuf1, arr, red);
  } else {
    run_group<8, 16, 0, 3>(3, 1536 + (bid - 192) * 8, 1024, 0.0f,
        inp, inhib, s2s_f, t2s, a2s, s2n, n2t, t2a, a2a, inpw,
        out_hn, out_rnn, hbuf0, hbuf1, arr, red);
  }
}

extern "C" void kernel_launch(void* const* d_in, const int* in_sizes, int n_in,
                              void* d_out, int out_size, void* d_ws, size_t ws_size,
                              hipStream_t stream) {
  const float* inp   = (const float*)d_in[0];   // [32,1000,1]
  const float* hn    = (const float*)d_in[1];   // [1,32,2048]
  const float* inhib = (const float*)d_in[2];   // [32,1000,2048]
  // d_in[3] = str2str_w (x0.0 in reference -> unused)
  const float* t2a   = (const float*)d_in[4];
  const float* t2s   = (const float*)d_in[5];
  const float* a2a   = (const float*)d_in[6];
  const float* a2s   = (const float*)d_in[7];
  const float* s2n   = (const float*)d_in[8];
  const float* n2t   = (const float*)d_in[9];
  const float* inpw  = (const float*)d_in[10];
  const float* s2s_f = (const float*)d_in[11];

  float* out_hn  = (float*)d_out;               // [1,32,2048]
  float* out_rnn = out_hn + BATCHN * H4T;       // [32,1000,2048]

  float* hbuf0 = (float*)d_ws;
  float* hbuf1 = hbuf0 + BATCHN * H4T;
  unsigned int* arr = (unsigned int*)((char*)d_ws + 512 * 1024);

  hipMemsetAsync(arr, 0, TSTEPS * NBLK * sizeof(unsigned int), stream);
  prep_h0<<<256, 256, 0, stream>>>(hn, hbuf0);
  rnn_persistent<<<NBLK, NTHR, 0, stream>>>(
      inp, inhib, s2s_f, t2s, a2s, s2n, n2t, t2a, a2a, inpw,
      out_hn, out_rnn, hbuf0, hbuf1, arr);
}